// Round 2
// baseline (14128.119 us; speedup 1.0000x reference)
//
#include <hip/hip_runtime.h>
#include <math.h>

// Problem constants
#define Vv 32000
#define Ee 512
#define Hh 1024
#define H3 3072
#define Ss 64
#define Bb 32
#define DEC_T 63
#define PAD_TOK 1
#define NEGV -100000.0f

typedef unsigned short ushort_t;
typedef __attribute__((ext_vector_type(8))) __bf16 bf16x8;
typedef __attribute__((ext_vector_type(4))) float f32x4;

__device__ __forceinline__ float sigmoidf_(float x) {
  return 1.0f / (1.0f + __expf(-x));
}

// ==================== generic fp32 GEMM (gx precompute, cc, fallback logits)
// C[m][n] = sum_k A[m][k]*W[n][k] + bias[n]; A rows optionally gathered via idx.
template <int ACT>
__global__ __launch_bounds__(256) void gemm_nt(
    const float* __restrict__ A, const int* __restrict__ idx, int lda,
    const float* __restrict__ W, int ldw,
    const float* __restrict__ bias,
    float* __restrict__ C, long ldc,
    int M, int N, int K) {
  __shared__ float As[8][132];
  __shared__ float Ws[8][132];
  int tid = threadIdx.x;
  int n0 = blockIdx.x * 128;
  int m0 = blockIdx.y * 128;
  int sr = tid >> 1;
  int sk = (tid & 1) * 4;
  int am = m0 + sr;
  bool aval = am < M;
  int amc = aval ? am : (M - 1);
  const float* arow = A + (idx ? (long)idx[amc] * lda : (long)amc * lda);
  const float* wrow = W + (long)(n0 + sr) * ldw;
  int tx = tid & 15, ty = tid >> 4;
  float acc[8][8];
#pragma unroll
  for (int i = 0; i < 8; i++)
#pragma unroll
    for (int j = 0; j < 8; j++) acc[i][j] = 0.f;

  for (int k0 = 0; k0 < K; k0 += 8) {
    float4 av = aval ? *(const float4*)(arow + k0 + sk) : make_float4(0.f, 0.f, 0.f, 0.f);
    float4 wv = *(const float4*)(wrow + k0 + sk);
    __syncthreads();
    As[sk + 0][sr] = av.x; As[sk + 1][sr] = av.y; As[sk + 2][sr] = av.z; As[sk + 3][sr] = av.w;
    Ws[sk + 0][sr] = wv.x; Ws[sk + 1][sr] = wv.y; Ws[sk + 2][sr] = wv.z; Ws[sk + 3][sr] = wv.w;
    __syncthreads();
#pragma unroll
    for (int k = 0; k < 8; k++) {
      float a[8], w[8];
      *(float4*)(a) = *(const float4*)&As[k][ty * 8];
      *(float4*)(a + 4) = *(const float4*)&As[k][ty * 8 + 4];
      *(float4*)(w) = *(const float4*)&Ws[k][tx * 8];
      *(float4*)(w + 4) = *(const float4*)&Ws[k][tx * 8 + 4];
#pragma unroll
      for (int i = 0; i < 8; i++)
#pragma unroll
        for (int j = 0; j < 8; j++) acc[i][j] = fmaf(a[i], w[j], acc[i][j]);
    }
  }
#pragma unroll
  for (int i = 0; i < 8; i++) {
    int m = m0 + ty * 8 + i;
    if (m < M) {
      float* crow = C + (long)m * ldc + n0 + tx * 8;
#pragma unroll
      for (int j = 0; j < 8; j++) {
        float v = acc[i][j] + bias[n0 + tx * 8 + j];
        if (ACT == 1) v = tanhf(v);
        crow[j] = v;
      }
    }
  }
}

// ==================== fused persistent 2-layer GRU recurrence ====================
// grid = 256 blocks x 768 threads, 1 block/CU (forced by 152.8KB LDS => barrier
// co-residency guaranteed). Block owns 4 hidden units; its 12 weight rows per
// matrix live in LDS for all steps. One device-scope grid barrier per step
// (monotone counter, no reset => no reset/arrive race).

__device__ __forceinline__ void gbar_(unsigned* cnt, unsigned target) {
  __syncthreads();                 // drains vmcnt before barrier (compiler-enforced)
  if (threadIdx.x == 0) {
    __threadfence();               // release: write back L2 -> LLC
    __hip_atomic_fetch_add(cnt, 1u, __ATOMIC_ACQ_REL, __HIP_MEMORY_SCOPE_AGENT);
    while (__hip_atomic_load(cnt, __ATOMIC_RELAXED, __HIP_MEMORY_SCOPE_AGENT) < target)
      __builtin_amdgcn_s_sleep(2);
  }
  __syncthreads();
  __threadfence();                 // acquire: invalidate L1/L2 so loads see fresh data
}

// one dot-pass: thread covers k-slice {kh*4 + 16j}, batches bp and bp+16;
// 4-lane-quad partials reduced via shfl_xor. All pointers pre-offset by kh*4.
__device__ __forceinline__ void dotpass_(const float* __restrict__ wrow,
                                         const float* __restrict__ hA,
                                         const float* __restrict__ hB,
                                         float& dA, float& dB) {
  float a0 = 0.f, a1 = 0.f, a2 = 0.f, a3 = 0.f;
  float b0 = 0.f, b1 = 0.f, b2 = 0.f, b3 = 0.f;
#pragma unroll 8
  for (int j = 0; j < 64; j++) {
    float4 w4 = *(const float4*)(wrow + j * 16);
    float4 xa = *(const float4*)(hA + j * 16);
    float4 xb = *(const float4*)(hB + j * 16);
    a0 = fmaf(w4.x, xa.x, a0); a1 = fmaf(w4.y, xa.y, a1);
    a2 = fmaf(w4.z, xa.z, a2); a3 = fmaf(w4.w, xa.w, a3);
    b0 = fmaf(w4.x, xb.x, b0); b1 = fmaf(w4.y, xb.y, b1);
    b2 = fmaf(w4.z, xb.z, b2); b3 = fmaf(w4.w, xb.w, b3);
  }
  float dA_ = (a0 + a1) + (a2 + a3);
  float dB_ = (b0 + b1) + (b2 + b3);
  dA_ += __shfl_xor(dA_, 1); dA_ += __shfl_xor(dA_, 2);
  dB_ += __shfl_xor(dB_, 1); dB_ += __shfl_xor(dB_, 2);
  dA = dA_; dB = dB_;
}

__global__ __launch_bounds__(768) void recur_k(
    const float* __restrict__ Whh0, const float* __restrict__ Wih1,
    const float* __restrict__ Whh1, const float* __restrict__ bhh0,
    const float* __restrict__ bih1, const float* __restrict__ bhh1,
    const float* __restrict__ gx,      // [steps][32][3072]
    float* __restrict__ h0,            // [2][32][1024] ping-pong
    float* __restrict__ h1,            // [2][32][1024]
    float* __restrict__ out2,          // enc_out or h1cat(first half)
    long o2r, long o2s, int steps, unsigned barBase,
    unsigned* __restrict__ bar) {
  __shared__ float w0[12][1028], w1x[12][1028], w1h[12][1028];  // 148032 B
  __shared__ float sg0[12][32], sgx[12][32], sgh[12][32];
  __shared__ float bia0[12], b1xs[12], b1hs[12];

  const int tid = threadIdx.x;
  const int u0 = blockIdx.x * 4;

  // stage this block's weight rows (row r = gate g*4 + unit u -> global row g*1024+u0+u)
  for (int i = tid; i < 3072; i += 768) {
    int r = i >> 8;
    int k4 = (i & 255) << 2;
    int g = r >> 2, u = r & 3;
    long src = (long)(g * 1024 + u0 + u) * 1024 + k4;
    *(float4*)&w0[r][k4]  = *(const float4*)(Whh0 + src);
    *(float4*)&w1x[r][k4] = *(const float4*)(Wih1 + src);
    *(float4*)&w1h[r][k4] = *(const float4*)(Whh1 + src);
  }
  if (tid < 12) {
    int g = tid >> 2, u = tid & 3;
    bia0[tid] = bhh0[g * 1024 + u0 + u];
    b1xs[tid] = bih1[g * 1024 + u0 + u];
    b1hs[tid] = bhh1[g * 1024 + u0 + u];
  }
  __syncthreads();

  const int kh4 = (tid & 3) << 2;   // k-slice start: {kh*4 + 16j}
  const int c   = (tid >> 2) % 12;  // output column (gate*4+unit)
  const int bp  = tid / 48;         // batch pair base (bp, bp+16)
  const int ub  = tid & 3, bb = tid >> 2;  // update-phase ids (tid<128)

  int p0 = 0, p1 = 0;
  for (int s = 0; s < steps; s++) {
    // prefetch update inputs early (latency hidden behind dots)
    float gxr = 0.f, gxz = 0.f, gxn = 0.f, h0old = 0.f;
    if (tid < 128) {
      const float* gp = gx + ((long)s * 32 + bb) * 3072 + u0 + ub;
      gxr = gp[0]; gxz = gp[1024]; gxn = gp[2048];
      h0old = h0[p0 * 32768 + bb * 1024 + u0 + ub];
    }
    // ---- layer0 dots: gh0 = h0 @ Whh0^T (block's 12 columns) ----
    {
      const float* hb = h0 + p0 * 32768 + kh4;
      float dA, dB;
      dotpass_(&w0[c][kh4], hb + bp * 1024, hb + (bp + 16) * 1024, dA, dB);
      if ((tid & 3) == 0) { sg0[c][bp] = dA; sg0[c][bp + 16] = dB; }
    }
    __syncthreads();
    // ---- layer0 GRU update (in-block: we own these units) ----
    if (tid < 128) {
      float rr = sigmoidf_(gxr + sg0[ub][bb] + bia0[ub]);
      float zz = sigmoidf_(gxz + sg0[4 + ub][bb] + bia0[4 + ub]);
      float nn = tanhf(gxn + rr * (sg0[8 + ub][bb] + bia0[8 + ub]));
      h0[(p0 ^ 1) * 32768 + bb * 1024 + u0 + ub] = (1.f - zz) * nn + zz * h0old;
    }
    p0 ^= 1;
    gbar_(bar, (barBase + (unsigned)s + 1u) * 256u);  // publish h0(new) to all blocks
    float h1old = 0.f;
    if (tid < 128) h1old = h1[p1 * 32768 + bb * 1024 + u0 + ub];
    // ---- layer1 dots: gx1 = h0new @ Wih1^T, gh1 = h1 @ Whh1^T ----
    {
      const float* xb = h0 + p0 * 32768 + kh4;
      const float* hb = h1 + p1 * 32768 + kh4;
      float xA, xB, hA, hB;
      dotpass_(&w1x[c][kh4], xb + bp * 1024, xb + (bp + 16) * 1024, xA, xB);
      dotpass_(&w1h[c][kh4], hb + bp * 1024, hb + (bp + 16) * 1024, hA, hB);
      if ((tid & 3) == 0) {
        sgx[c][bp] = xA; sgx[c][bp + 16] = xB;
        sgh[c][bp] = hA; sgh[c][bp + 16] = hB;
      }
    }
    __syncthreads();
    // ---- layer1 GRU update + output row ----
    if (tid < 128) {
      float rr = sigmoidf_(sgx[ub][bb] + b1xs[ub] + sgh[ub][bb] + b1hs[ub]);
      float zz = sigmoidf_(sgx[4 + ub][bb] + b1xs[4 + ub] + sgh[4 + ub][bb] + b1hs[4 + ub]);
      float nn = tanhf(sgx[8 + ub][bb] + b1xs[8 + ub] + rr * (sgh[8 + ub][bb] + b1hs[8 + ub]));
      float hv = (1.f - zz) * nn + zz * h1old;
      h1[(p1 ^ 1) * 32768 + bb * 1024 + u0 + ub] = hv;
      out2[(long)s * o2s + (long)bb * o2r + u0 + ub] = hv;
    }
    p1 ^= 1;
    // no second barrier needed: h1(new) is published by next step's barrier,
    // and double-buffering makes all read/write sets disjoint in between.
  }
}

// ==================== attention scores + masked softmax (one block per (t,b))
__global__ __launch_bounds__(256) void attn_kernel(
    const float* __restrict__ h1cat, const float* __restrict__ enc_out,
    const int* __restrict__ src_tok, float* __restrict__ attn) {
  int tb = blockIdx.x;
  int b = tb & 31;
  __shared__ float hs[1024];
  __shared__ float sc[64][4];
  __shared__ float red[64];
  int tid = threadIdx.x;
  const float* h1 = h1cat + (long)tb * 2048;
  for (int i = tid; i < 1024; i += 256) hs[i] = h1[i];
  __syncthreads();
  int s = tid >> 2, q = tid & 3;
  const float* eo = enc_out + ((long)s * Bb + b) * Hh + q * 256;
  float p = 0.f;
  for (int k = 0; k < 256; k += 4) {
    float4 e = *(const float4*)(eo + k);
    const float* hq = hs + q * 256 + k;
    p += e.x * hq[0] + e.y * hq[1] + e.z * hq[2] + e.w * hq[3];
  }
  sc[s][q] = p;
  __syncthreads();
  if (tid < 64) {
    float v = sc[tid][0] + sc[tid][1] + sc[tid][2] + sc[tid][3];
    bool m = (src_tok[tid * Bb + b] != PAD_TOK);
    red[tid] = m ? v : NEGV;
  }
  __syncthreads();
  if (tid < 64) {
    float v = red[tid];
    float mx = v;
    for (int o = 32; o; o >>= 1) mx = fmaxf(mx, __shfl_xor(mx, o));
    float e = __expf(v - mx);
    float sum = e;
    for (int o = 32; o; o >>= 1) sum += __shfl_xor(sum, o);
    attn[(long)tb * 64 + tid] = e / sum;
  }
}

// ==================== context ====================
__global__ __launch_bounds__(256) void ctx_kernel(
    const float* __restrict__ attn, const float* __restrict__ enc_out,
    float* __restrict__ h1cat) {
  int tb = blockIdx.x;
  int b = tb & 31;
  __shared__ float as[64];
  int tid = threadIdx.x;
  if (tid < 64) as[tid] = attn[(long)tb * 64 + tid];
  __syncthreads();
  float4 acc = make_float4(0.f, 0.f, 0.f, 0.f);
  const float* eo = enc_out + (long)b * Hh + tid * 4;
  for (int s = 0; s < 64; s++) {
    float a = as[s];
    float4 e = *(const float4*)(eo + (long)s * Bb * Hh);
    acc.x += a * e.x; acc.y += a * e.y; acc.z += a * e.z; acc.w += a * e.w;
  }
  *(float4*)(h1cat + (long)tb * 2048 + 1024 + tid * 4) = acc;
}

// ==================== bf16 hi/lo split (x = hi + lo exactly to ~2^-17 rel)
__device__ __forceinline__ ushort_t f2bf_(float x) {
  unsigned u = __float_as_uint(x);
  unsigned r = (u + 0x7fffu + ((u >> 16) & 1u)) >> 16;
  return (ushort_t)r;
}
__device__ __forceinline__ float bf2f_(ushort_t h) {
  return __uint_as_float(((unsigned)h) << 16);
}

__global__ __launch_bounds__(256) void split_k(
    const float* __restrict__ src, ushort_t* __restrict__ hi,
    ushort_t* __restrict__ lo, long n) {
  long i = ((long)blockIdx.x * 256 + threadIdx.x) * 4;
  if (i >= n) return;
  float4 v = *(const float4*)(src + i);
  ushort_t h0 = f2bf_(v.x), h1 = f2bf_(v.y), h2 = f2bf_(v.z), h3 = f2bf_(v.w);
  ushort_t l0 = f2bf_(v.x - bf2f_(h0)), l1 = f2bf_(v.y - bf2f_(h1));
  ushort_t l2 = f2bf_(v.z - bf2f_(h2)), l3 = f2bf_(v.w - bf2f_(h3));
  ushort4 hv; hv.x = h0; hv.y = h1; hv.z = h2; hv.w = h3;
  ushort4 lv; lv.x = l0; lv.y = l1; lv.z = l2; lv.w = l3;
  *(ushort4*)(hi + i) = hv;
  *(ushort4*)(lo + i) = lv;
}

// ==================== split-bf16 MFMA logits GEMM ====================
// C[m][n] = A[m][:] . W[n][:] + bias[n]  via  Ah.Wh + Ah.Wl + Al.Wh
// 128x128 tile, BK=32, 4 waves, mfma_f32_16x16x32_bf16, XOR-swizzled LDS.
__global__ __launch_bounds__(256) void gemm_logits(
    const ushort_t* __restrict__ Ah, const ushort_t* __restrict__ Al,
    const ushort_t* __restrict__ Wh, const ushort_t* __restrict__ Wl,
    const float* __restrict__ bias, float* __restrict__ C, int M) {
  __shared__ ushort_t As[128 * 32];
  __shared__ ushort_t Bs[128 * 32];
  int tid = threadIdx.x;
  int n0 = blockIdx.x * 128, m0 = blockIdx.y * 128;
  int wave = tid >> 6, lane = tid & 63;
  int wm = wave & 1, wn = wave >> 1;
  int lm = lane & 15, lq = lane >> 4;
  f32x4 acc[4][4];
#pragma unroll
  for (int i = 0; i < 4; i++)
#pragma unroll
    for (int j = 0; j < 4; j++) acc[i][j] = (f32x4){0.f, 0.f, 0.f, 0.f};

  int srow = tid >> 2;          // 0..63
  int skq = tid & 3;            // 16B chunk index
  int chunkw = skq ^ (srow & 3);  // swizzled store position

  for (int pass = 0; pass < 3; pass++) {
    const ushort_t* Ap = (pass < 2) ? Ah : Al;
    const ushort_t* Wp = (pass == 1) ? Wl : Wh;
    for (int k0 = 0; k0 < 1024; k0 += 32) {
      int r0 = m0 + srow;      r0 = r0 < M ? r0 : M - 1;
      int r1 = m0 + 64 + srow; r1 = r1 < M ? r1 : M - 1;
      uint4 a0 = *(const uint4*)(Ap + (long)r0 * 1024 + k0 + skq * 8);
      uint4 a1 = *(const uint4*)(Ap + (long)r1 * 1024 + k0 + skq * 8);
      uint4 b0 = *(const uint4*)(Wp + (long)(n0 + srow) * 1024 + k0 + skq * 8);
      uint4 b1 = *(const uint4*)(Wp + (long)(n0 + 64 + srow) * 1024 + k0 + skq * 8);
      __syncthreads();
      *(uint4*)&As[srow * 32 + chunkw * 8] = a0;
      *(uint4*)&As[(64 + srow) * 32 + chunkw * 8] = a1;   // (64+srow)&3 == srow&3
      *(uint4*)&Bs[srow * 32 + chunkw * 8] = b0;
      *(uint4*)&Bs[(64 + srow) * 32 + chunkw * 8] = b1;
      __syncthreads();
      bf16x8 af[4], bf[4];
#pragma unroll
      for (int mi = 0; mi < 4; mi++) {
        int r = wm * 64 + mi * 16 + lm;
        af[mi] = *(const bf16x8*)&As[r * 32 + ((lq ^ (r & 3)) * 8)];
      }
#pragma unroll
      for (int nj = 0; nj < 4; nj++) {
        int r = wn * 64 + nj * 16 + lm;
        bf[nj] = *(const bf16x8*)&Bs[r * 32 + ((lq ^ (r & 3)) * 8)];
      }
#pragma unroll
      for (int mi = 0; mi < 4; mi++)
#pragma unroll
        for (int nj = 0; nj < 4; nj++)
          acc[mi][nj] = __builtin_amdgcn_mfma_f32_16x16x32_bf16(
              af[mi], bf[nj], acc[mi][nj], 0, 0, 0);
    }
  }
  // epilogue: C row = (lq*4+reg) within tile (A side), col = lm (W side)
#pragma unroll
  for (int mi = 0; mi < 4; mi++) {
#pragma unroll
    for (int nj = 0; nj < 4; nj++) {
      int mbase = m0 + wm * 64 + mi * 16 + lq * 4;
      int n = n0 + wn * 64 + nj * 16 + lm;
      float bv = bias[n];
#pragma unroll
      for (int r = 0; r < 4; r++) {
        int m = mbase + r;
        if (m < M) C[(long)m * Vv + n] = acc[mi][nj][r] + bv;
      }
    }
  }
}

extern "C" void kernel_launch(void* const* d_in, const int* in_sizes, int n_in,
                              void* d_out, int out_size, void* d_ws, size_t ws_size,
                              hipStream_t stream) {
  const int* src_tok = (const int*)d_in[0];
  const int* tgt_tok = (const int*)d_in[1];
  const float* enc_emb = (const float*)d_in[2];
  const float* eWih0 = (const float*)d_in[3];
  const float* eWhh0 = (const float*)d_in[4];
  const float* ebih0 = (const float*)d_in[5];
  const float* ebhh0 = (const float*)d_in[6];
  const float* eWih1 = (const float*)d_in[7];
  const float* eWhh1 = (const float*)d_in[8];
  const float* ebih1 = (const float*)d_in[9];
  const float* ebhh1 = (const float*)d_in[10];
  const float* dec_emb = (const float*)d_in[11];
  const float* dWih0 = (const float*)d_in[12];
  const float* dWhh0 = (const float*)d_in[13];
  const float* dbih0 = (const float*)d_in[14];
  const float* dbhh0 = (const float*)d_in[15];
  const float* dWih1 = (const float*)d_in[16];
  const float* dWhh1 = (const float*)d_in[17];
  const float* dbih1 = (const float*)d_in[18];
  const float* dbhh1 = (const float*)d_in[19];
  const float* Wc = (const float*)d_in[20];
  const float* bc = (const float*)d_in[21];
  const float* Wo = (const float*)d_in[22];
  const float* bo = (const float*)d_in[23];
  float* out = (float*)d_out;

  // ---- workspace layout (float units) ----
  float* w = (float*)d_ws;
  size_t o = 0;
  float* gx0 = w + o;     o += (size_t)Ss * Bb * H3;        // 6,291,456
  float* enc_out = w + o; o += (size_t)Ss * Bb * Hh;        // 2,097,152
  float* h1cat = w + o;   o += (size_t)DEC_T * Bb * 2 * Hh; // 4,128,768
  float* h0buf = w + o;   o += (size_t)2 * Bb * Hh;         // 65,536 (ping-pong)
  float* h1buf = w + o;   o += (size_t)2 * Bb * Hh;         // adjacent to h0buf
  float* attnb = w + o;   o += (size_t)DEC_T * Bb * Ss;
  float* ccb = w + o;     o += (size_t)DEC_T * Bb * Hh;
  unsigned* bar = (unsigned*)(w + o); o += 16;
  ushort_t* Ah = (ushort_t*)(w + o); o += (size_t)DEC_T * Bb * Hh / 2;
  ushort_t* Al = (ushort_t*)(w + o); o += (size_t)DEC_T * Bb * Hh / 2;
  ushort_t* Wh = (ushort_t*)(w + o); o += (size_t)Vv * Hh / 2;
  ushort_t* Wl = (ushort_t*)(w + o); o += (size_t)Vv * Hh / 2;
  const size_t FULL_BYTES = o * sizeof(float);   // ~198.7 MB
  bool use_mfma = ws_size >= FULL_BYTES;

  // zero first output timestep, initial hidden state, barrier counter
  hipMemsetAsync(out, 0, (size_t)Bb * Vv * sizeof(float), stream);
  hipMemsetAsync(h0buf, 0, (size_t)4 * Bb * Hh * sizeof(float), stream);  // h0+h1 both parities
  hipMemsetAsync(bar, 0, 8, stream);

  // encoder input gates for all timesteps
  gemm_nt<0><<<dim3(H3 / 128, 16), 256, 0, stream>>>(
      enc_emb, src_tok, Ee, eWih0, Ee, ebih0, gx0, (long)H3, Ss * Bb, H3, Ee);

  // ---- fused encoder recurrence (64 steps, 1 launch) ----
  recur_k<<<256, 768, 0, stream>>>(eWhh0, eWih1, eWhh1, ebhh0, ebih1, ebhh1,
                                   gx0, h0buf, h1buf, enc_out,
                                   (long)Hh, (long)(Bb * Hh), Ss, 0u, bar);

  // decoder input gates (reuses gx0; stream-ordered after enc recur)
  gemm_nt<0><<<dim3(H3 / 128, 16), 256, 0, stream>>>(
      dec_emb, tgt_tok, Ee, dWih0, Ee, dbih0, gx0, (long)H3, DEC_T * Bb, H3, Ee);

  // ---- fused decoder recurrence (63 steps, 1 launch; hidden carries over) ----
  recur_k<<<256, 768, 0, stream>>>(dWhh0, dWih1, dWhh1, dbhh0, dbih1, dbhh1,
                                   gx0, h0buf, h1buf, h1cat,
                                   (long)(2 * Hh), (long)(Bb * 2 * Hh), DEC_T, (unsigned)Ss, bar);

  // ---- batched attention + context (deferred: doesn't feed the recurrence) ----
  attn_kernel<<<DEC_T * Bb, 256, 0, stream>>>(h1cat, enc_out, src_tok, attnb);
  ctx_kernel<<<DEC_T * Bb, 256, 0, stream>>>(attnb, enc_out, h1cat);

  // cc = tanh([h1, ctx] @ Wc^T + bc)
  gemm_nt<1><<<dim3(Hh / 128, 16), 256, 0, stream>>>(
      h1cat, nullptr, 2 * Hh, Wc, 2 * Hh, bc, ccb, (long)Hh, DEC_T * Bb, Hh, 2 * Hh);

  // logits = cc @ Wo^T + bo -> rows [1..63] of output
  if (use_mfma) {
    split_k<<<(Vv * Hh) / 1024, 256, 0, stream>>>(Wo, Wh, Wl, (long)Vv * Hh);
    split_k<<<(DEC_T * Bb * Hh) / 1024, 256, 0, stream>>>(ccb, Ah, Al, (long)DEC_T * Bb * Hh);
    gemm_logits<<<dim3(Vv / 128, 16), 256, 0, stream>>>(
        Ah, Al, Wh, Wl, bo, out + (size_t)Bb * Vv, DEC_T * Bb);
  } else {
    gemm_nt<0><<<dim3(Vv / 128, 16), 256, 0, stream>>>(
        ccb, nullptr, Hh, Wo, Hh, bo, out + (size_t)Bb * Vv, (long)Vv, DEC_T * Bb, Vv, Hh);
  }
}